// Round 9
// baseline (104.976 us; speedup 1.0000x reference)
//
#include <hip/hip_runtime.h>

constexpr int Bn = 65536;   // rows (entity pairs)
constexpr int Cn = 512;     // relation classes

#define L2E 1.4426950408889634f
#define LN2 0.6931471805599453f

typedef float f32x4 __attribute__((ext_vector_type(4)));

// Global->LDS DMA: no VGPR destination, so the register allocator cannot
// serialize the pipeline. HW writes lane l's 16B to ldsbase + l*16.
__device__ __forceinline__ void gl2lds16(const float* g, float* l) {
  __builtin_amdgcn_global_load_lds(
      (const __attribute__((address_space(1))) void*)g,
      (__attribute__((address_space(3))) void*)l, 16, 0, 0);
}

__device__ __forceinline__ uint32_t lds_addr(const void* p) {
  return (uint32_t)(uintptr_t)(__attribute__((address_space(3))) const char*)(const char*)p;
}

// One row per wave, 8 rows/wave (stride 8192), processed as 16 half-row
// chunks (256 cols logits + 256 cols labels = 2KB = 2 global_load_lds).
// 2-chunk LDS double buffer = 4KB/wave -> 16.4KB/block -> 8 blocks/CU at
// __launch_bounds__(256,8): 32 waves/CU (2x round 8). Counted vmcnt(2)
// keeps the next chunk's loads in flight across every compute phase.
__global__ __launch_bounds__(256, 8) void matloss_main(
    const float* __restrict__ logits,
    const float* __restrict__ labels,
    double* __restrict__ acc) {

  const int lane = threadIdx.x & 63;
  const int wib  = threadIdx.x >> 6;
  const int gw   = blockIdx.x * 4 + wib;        // 8192 waves, all resident
  constexpr int NW = 8192;                      // row stride between row-steps
  constexpr int NC = 16;                        // chunks per wave (8 rows x 2)

  __shared__ float smem[4 * 2 * 512];           // [wave][slot][512 floats]
  float* slot0 = &smem[wib * 1024];             // chunk: lg half (256) + lb half (256)
  float* slot1 = slot0 + 512;

  auto stage = [&](int c, float* slot) {        // 2 vmem ops, 2KB, zero VGPRs
    const size_t row = (size_t)(gw + (c >> 1) * NW);
    const int    col = (c & 1) * 256;
    gl2lds16(logits + row * Cn + col + lane * 4, slot);
    gl2lds16(labels + row * Cn + col + lane * 4, slot + 256);
  };

  stage(0, slot0);                              // prologue: 4 loads in flight
  stage(1, slot1);

  const uint32_t a0 = lds_addr(slot0) + lane * 16;
  const uint32_t a1 = a0 + 2048;

  float a_term = 0.f, a_cnt = 0.f, a_l2 = 0.f;
  float P = 1.f, S = 0.f, PM = 0.f, CN = 0.f, x0 = 0.f;

#pragma unroll
  for (int i = 0; i < NC; ++i) {
    if (i == NC - 1) asm volatile("s_waitcnt vmcnt(0)" ::: "memory");
    else             asm volatile("s_waitcnt vmcnt(2)" ::: "memory");  // counted, never 0
    __builtin_amdgcn_sched_barrier(0);

    f32x4 xv, lv;
    asm volatile("ds_read_b128 %0, %2\n\t"
                 "ds_read_b128 %1, %2 offset:1024"
                 : "=&v"(xv), "=&v"(lv) : "v"((i & 1) ? a1 : a0));
    asm volatile("s_waitcnt lgkmcnt(0)" ::: "memory");
    __builtin_amdgcn_sched_barrier(0);          // rule #18: no consumer hoisting

    if (i + 2 < NC) stage(i + 2, (i & 1) ? slot1 : slot0);  // refill under compute

    float x[4] = {xv.x, xv.y, xv.z, xv.w};
    float l[4] = {lv.x, lv.y, lv.z, lv.w};

    if ((i & 1) == 0) {                         // first half of a new row
      P = 1.f; S = 0.f; PM = 0.f; CN = 0.f;
      if (lane == 0) l[0] = 0.f;                // threshold class: label forced 0
      x0 = x[0];                                // lane 0 holds logits[row,0]
    }

    // P  = prod over positives of (1 + exp(-|x|))   (one log per row)
    // PM = sum  over positives of min(x, 0)
    // S  = sum  over negatives of exp(x)            (no-max LSE: |x| < ~6)
#pragma unroll
    for (int k = 0; k < 4; ++k) {
      bool  pos = (l[k] != 0.f);
      float sel = pos ? -fabsf(x[k]) : x[k];
      float e   = __builtin_amdgcn_exp2f(sel * L2E);
      P  *= fmaf(l[k], e, 1.f);
      S  += pos ? 0.f : e;
      PM  = fmaf(l[k], fminf(x[k], 0.f), PM);
      CN += l[k];
    }

    if (i & 1) {                                // row complete: reduce + finalize
#pragma unroll
      for (int off = 32; off; off >>= 1) {      // 6-step butterfly, 4 chains
        S  += __shfl_xor(S,  off);
        CN += __shfl_xor(CN, off);
        PM += __shfl_xor(PM, off);
        P  *= __shfl_xor(P,  off);
      }
      float xz = __shfl(x0, 0);                 // logits[row, 0]
      a_l2 += LN2 * __builtin_amdgcn_logf(S) - xz;   // lse - x0
      if (CN > 0.f) {                           // wave-uniform branch
        float t0  = __builtin_amdgcn_exp2f(-fabsf(xz) * L2E);
        float ls0 = fminf(-xz, 0.f) - LN2 * __builtin_amdgcn_logf(1.f + t0);
        a_term += ls0 + PM - LN2 * __builtin_amdgcn_logf(P);
        a_cnt  += 1.f + CN;
      }
    }
  }

  __shared__ float sm[3][4];
  if (lane == 0) { sm[0][wib] = a_term; sm[1][wib] = a_cnt; sm[2][wib] = a_l2; }
  __syncthreads();
  if (threadIdx.x == 0) {
    atomicAdd(&acc[0], (double)(sm[0][0] + sm[0][1] + sm[0][2] + sm[0][3]));
    atomicAdd(&acc[1], (double)(sm[1][0] + sm[1][1] + sm[1][2] + sm[1][3]));
    atomicAdd(&acc[2], (double)(sm[2][0] + sm[2][1] + sm[2][2] + sm[2][3]));
  }
}

__global__ void matloss_final(const double* __restrict__ acc, float* __restrict__ out) {
  out[0] = (float)(-acc[0] / acc[1] + acc[2] / (double)Bn);
}

extern "C" void kernel_launch(void* const* d_in, const int* in_sizes, int n_in,
                              void* d_out, int out_size, void* d_ws, size_t ws_size,
                              hipStream_t stream) {
  const float* logits = (const float*)d_in[0];
  const float* labels = (const float*)d_in[1];
  float* out = (float*)d_out;
  double* acc = (double*)d_ws;

  hipMemsetAsync(d_ws, 0, 3 * sizeof(double), stream);  // zero accumulators (capture-safe)
  matloss_main<<<2048, 256, 0, stream>>>(logits, labels, acc);
  matloss_final<<<1, 1, 0, stream>>>(acc, out);
}

// Round 10
// 71.333 us; speedup vs baseline: 1.4716x; 1.4716x over previous
//
#include <hip/hip_runtime.h>

constexpr int Bn = 65536;   // rows (entity pairs)
constexpr int Cn = 512;     // relation classes

#define L2E 1.4426950408889634f
#define LN2 0.6931471805599453f

typedef float f32x4 __attribute__((ext_vector_type(4)));

// Global->LDS DMA: no VGPR destination, so the register allocator cannot
// serialize the pipeline. HW writes lane l's 16B to ldsbase + l*16.
__device__ __forceinline__ void gl2lds16(const float* g, float* l) {
  __builtin_amdgcn_global_load_lds(
      (const __attribute__((address_space(1))) void*)g,
      (__attribute__((address_space(3))) void*)l, 16, 0, 0);
}

__device__ __forceinline__ uint32_t lds_addr(const void* p) {
  return (uint32_t)(uintptr_t)(__attribute__((address_space(3))) const char*)(const char*)p;
}

// DPP lane-shuffle on the VALU pipe (zero DS-pipe traffic). Lanes that read
// an invalid source (or are masked off) receive `ident` via the old operand.
template <int Ctrl, int RowMask>
__device__ __forceinline__ float dpp_get(float x, float ident) {
  return __int_as_float(__builtin_amdgcn_update_dpp(
      __float_as_int(ident), __float_as_int(x), Ctrl, RowMask, 0xf, false));
}

__global__ __launch_bounds__(256, 4) void matloss_main(
    const float* __restrict__ logits,
    const float* __restrict__ labels,
    double* __restrict__ acc) {

  const int lane = threadIdx.x & 63;
  const int wib  = threadIdx.x >> 6;
  const int gw   = blockIdx.x * 4 + wib;        // 4096 waves, all resident
  constexpr int NW = 4096;                      // row stride between iterations
  constexpr int R  = 16;                        // rows per wave

  __shared__ float smem[4 * 2 * 1024];          // [wave][slot][1024 floats]
  float* slot0 = &smem[wib * 2048];             // slot: lg lo/hi + lb lo/hi (4KB)
  float* slot1 = slot0 + 1024;

  auto stage = [&](int i, float* slot) {        // 4 vmem ops, 4KB, zero VGPRs
    const float* gl = logits + (size_t)(gw + i * NW) * Cn + lane * 4;
    const float* gb = labels + (size_t)(gw + i * NW) * Cn + lane * 4;
    gl2lds16(gl,       slot);
    gl2lds16(gl + 256, slot + 256);
    gl2lds16(gb,       slot + 512);
    gl2lds16(gb + 256, slot + 768);
  };

  stage(0, slot0);                              // prologue: 8 loads in flight
  stage(1, slot1);

  const uint32_t a0 = lds_addr(slot0) + lane * 16;
  const uint32_t a1 = lds_addr(slot1) + lane * 16;

  float a_term = 0.f, a_cnt = 0.f, a_l2 = 0.f;

#pragma unroll
  for (int i = 0; i < R; ++i) {
    if (i == R - 1) asm volatile("s_waitcnt vmcnt(0)" ::: "memory");
    else            asm volatile("s_waitcnt vmcnt(4)" ::: "memory");  // counted, never 0
    __builtin_amdgcn_sched_barrier(0);

    f32x4 xa, xb, la, lc;
    const uint32_t va = (i & 1) ? a1 : a0;
    asm volatile("ds_read_b128 %0, %4\n\t"
                 "ds_read_b128 %1, %4 offset:1024\n\t"
                 "ds_read_b128 %2, %4 offset:2048\n\t"
                 "ds_read_b128 %3, %4 offset:3072"
                 : "=&v"(xa), "=&v"(xb), "=&v"(la), "=&v"(lc)
                 : "v"(va));
    asm volatile("s_waitcnt lgkmcnt(0)" ::: "memory");
    __builtin_amdgcn_sched_barrier(0);          // rule #18: no consumer hoisting

    if (i + 2 < R) stage(i + 2, (i & 1) ? slot1 : slot0);  // refill under compute

    float x[8] = {xa.x, xa.y, xa.z, xa.w, xb.x, xb.y, xb.z, xb.w};
    float l[8] = {la.x, la.y, la.z, la.w, lc.x, lc.y, lc.z, lc.w};
    float xz = __int_as_float(__builtin_amdgcn_readfirstlane(__float_as_int(x[0])));
    if (lane == 0) l[0] = 0.f;                  // threshold class: label forced 0

    // P  = prod over positives of (1 + exp(-|x|))   (one log per row)
    // PM = sum  over positives of min(x, 0)
    // S  = sum  over negatives of exp(x)            (no-max LSE: |x| < ~6)
    float P = 1.f, S = 0.f, PM = 0.f, CN = 0.f;
#pragma unroll
    for (int k = 0; k < 8; ++k) {
      bool  pos = (l[k] != 0.f);
      float sel = pos ? -fabsf(x[k]) : x[k];
      float e   = __builtin_amdgcn_exp2f(sel * L2E);
      P  *= fmaf(l[k], e, 1.f);
      S  += pos ? 0.f : e;
      PM  = fmaf(l[k], fminf(x[k], 0.f), PM);
      CN += l[k];
    }

    // wave64 reduce on the VALU pipe: row_shr 1,2,4,8 then cross-row bcasts.
    // After this, lane 63 holds the wave total for each value.
#define RED4(CTRL, RM)                      \
    S  += dpp_get<CTRL, RM>(S,  0.f);       \
    CN += dpp_get<CTRL, RM>(CN, 0.f);       \
    PM += dpp_get<CTRL, RM>(PM, 0.f);       \
    P  *= dpp_get<CTRL, RM>(P,  1.f);
    RED4(0x111, 0xf)                        // row_shr:1
    RED4(0x112, 0xf)                        // row_shr:2
    RED4(0x114, 0xf)                        // row_shr:4
    RED4(0x118, 0xf)                        // row_shr:8
    RED4(0x142, 0xa)                        // row_bcast:15 (rows 1,3)
    RED4(0x143, 0xc)                        // row_bcast:31 (rows 2,3)
#undef RED4
    float Sw  = __int_as_float(__builtin_amdgcn_readlane(__float_as_int(S),  63));
    float CNw = __int_as_float(__builtin_amdgcn_readlane(__float_as_int(CN), 63));
    float PMw = __int_as_float(__builtin_amdgcn_readlane(__float_as_int(PM), 63));
    float Pw  = __int_as_float(__builtin_amdgcn_readlane(__float_as_int(P),  63));

    a_l2 += LN2 * __builtin_amdgcn_logf(Sw) - xz;   // lse - x0
    if (CNw > 0.f) {                          // wave-uniform branch
      float t0  = __builtin_amdgcn_exp2f(-fabsf(xz) * L2E);
      float ls0 = fminf(-xz, 0.f) - LN2 * __builtin_amdgcn_logf(1.f + t0);
      a_term += ls0 + PMw - LN2 * __builtin_amdgcn_logf(Pw);
      a_cnt  += 1.f + CNw;
    }
  }

  __shared__ float sm[3][4];
  if (lane == 0) { sm[0][wib] = a_term; sm[1][wib] = a_cnt; sm[2][wib] = a_l2; }
  __syncthreads();
  if (threadIdx.x == 0) {
    atomicAdd(&acc[0], (double)(sm[0][0] + sm[0][1] + sm[0][2] + sm[0][3]));
    atomicAdd(&acc[1], (double)(sm[1][0] + sm[1][1] + sm[1][2] + sm[1][3]));
    atomicAdd(&acc[2], (double)(sm[2][0] + sm[2][1] + sm[2][2] + sm[2][3]));
  }
}

__global__ void matloss_final(const double* __restrict__ acc, float* __restrict__ out) {
  out[0] = (float)(-acc[0] / acc[1] + acc[2] / (double)Bn);
}

extern "C" void kernel_launch(void* const* d_in, const int* in_sizes, int n_in,
                              void* d_out, int out_size, void* d_ws, size_t ws_size,
                              hipStream_t stream) {
  const float* logits = (const float*)d_in[0];
  const float* labels = (const float*)d_in[1];
  float* out = (float*)d_out;
  double* acc = (double*)d_ws;

  hipMemsetAsync(d_ws, 0, 3 * sizeof(double), stream);  // zero accumulators (capture-safe)
  matloss_main<<<1024, 256, 0, stream>>>(logits, labels, acc);
  matloss_final<<<1, 1, 0, stream>>>(acc, out);
}

// Round 11
// 59.371 us; speedup vs baseline: 1.7681x; 1.2015x over previous
//
#include <hip/hip_runtime.h>

constexpr int Bn = 65536;   // rows (entity pairs)
constexpr int Cn = 512;     // relation classes

#define L2E 1.4426950408889634f
#define LN2 0.6931471805599453f

typedef float f32x4 __attribute__((ext_vector_type(4)));

// Global->LDS DMA: no VGPR destination, so the register allocator cannot
// serialize the pipeline. HW writes lane l's 16B to ldsbase + l*16.
__device__ __forceinline__ void gl2lds16(const float* g, float* l) {
  __builtin_amdgcn_global_load_lds(
      (const __attribute__((address_space(1))) void*)g,
      (__attribute__((address_space(3))) void*)l, 16, 0, 0);
}

__device__ __forceinline__ uint32_t lds_addr(const void* p) {
  return (uint32_t)(uintptr_t)(__attribute__((address_space(3))) const char*)(const char*)p;
}

// DPP lane-shuffle on the VALU pipe (zero DS-pipe traffic).
template <int Ctrl, int RowMask>
__device__ __forceinline__ float dpp_get(float x, float ident) {
  return __int_as_float(__builtin_amdgcn_update_dpp(
      __float_as_int(ident), __float_as_int(x), Ctrl, RowMask, 0xf, false));
}

// TWO rows per wave per iteration (8KB slots, depth-2 double buffer =
// 16KB in flight/wave, vmcnt(8) steady). 512 blocks x 4 waves, 64KB LDS
// -> exactly 2 blocks/CU, one generation, zero tail. 32 rows/wave over
// 16 vmcnt-gated round trips (R9->R8->R10 gradient: fewer, fatter trips).
__global__ __launch_bounds__(256, 2) void matloss_main(
    const float* __restrict__ logits,
    const float* __restrict__ labels,
    double* __restrict__ acc) {

  const int lane = threadIdx.x & 63;
  const int wib  = threadIdx.x >> 6;
  const int gw   = blockIdx.x * 4 + wib;        // 2048 waves, all resident
  constexpr int NW = 2048;                      // row stride
  constexpr int IT = 16;                        // iterations (2 rows each)

  __shared__ float smem[4 * 2 * 2048];          // 64KB: [wave][slot][2048 f32]
  float* slot0 = &smem[wib * 4096];             // slot: rowA{lg 1K,lg 1K,lb 1K,lb 1K}
  float* slot1 = slot0 + 2048;                  //       rowB{same}  (8KB total)

  auto stage = [&](int i, float* slot) {        // 8 vmem ops, 8KB, zero VGPRs
#pragma unroll
    for (int r = 0; r < 2; ++r) {
      const size_t row = (size_t)(gw + (2 * i + r) * NW);
      const float* gl = logits + row * Cn + lane * 4;
      const float* gb = labels + row * Cn + lane * 4;
      float* s = slot + r * 1024;
      gl2lds16(gl,       s);
      gl2lds16(gl + 256, s + 256);
      gl2lds16(gb,       s + 512);
      gl2lds16(gb + 256, s + 768);
    }
  };

  stage(0, slot0);                              // prologue: 16 loads in flight
  stage(1, slot1);

  const uint32_t a0 = lds_addr(slot0) + lane * 16;
  const uint32_t a1 = a0 + 8192;

  float a_term = 0.f, a_cnt = 0.f, a_l2 = 0.f;

#pragma unroll
  for (int i = 0; i < IT; ++i) {
    if (i == IT - 1) asm volatile("s_waitcnt vmcnt(0)" ::: "memory");
    else             asm volatile("s_waitcnt vmcnt(8)" ::: "memory");  // counted, never 0
    __builtin_amdgcn_sched_barrier(0);

    f32x4 q[8];                                 // rowA: lg lo/hi, lb lo/hi; rowB: same
    const uint32_t va = (i & 1) ? a1 : a0;
    asm volatile("ds_read_b128 %0, %8\n\t"
                 "ds_read_b128 %1, %8 offset:1024\n\t"
                 "ds_read_b128 %2, %8 offset:2048\n\t"
                 "ds_read_b128 %3, %8 offset:3072\n\t"
                 "ds_read_b128 %4, %8 offset:4096\n\t"
                 "ds_read_b128 %5, %8 offset:5120\n\t"
                 "ds_read_b128 %6, %8 offset:6144\n\t"
                 "ds_read_b128 %7, %8 offset:7168"
                 : "=&v"(q[0]), "=&v"(q[1]), "=&v"(q[2]), "=&v"(q[3]),
                   "=&v"(q[4]), "=&v"(q[5]), "=&v"(q[6]), "=&v"(q[7])
                 : "v"(va));
    asm volatile("s_waitcnt lgkmcnt(0)" ::: "memory");
    __builtin_amdgcn_sched_barrier(0);          // rule #18: no consumer hoisting

    if (i + 2 < IT) stage(i + 2, (i & 1) ? slot1 : slot0);  // refill under compute

    float P[2], S[2], PM[2], CN[2], xz[2];
#pragma unroll
    for (int r = 0; r < 2; ++r) {               // unrolled: both rows' chains interleave
      f32x4 xa = q[4 * r], xb = q[4 * r + 1], la = q[4 * r + 2], lc = q[4 * r + 3];
      float x[8] = {xa.x, xa.y, xa.z, xa.w, xb.x, xb.y, xb.z, xb.w};
      float l[8] = {la.x, la.y, la.z, la.w, lc.x, lc.y, lc.z, lc.w};
      xz[r] = __int_as_float(__builtin_amdgcn_readfirstlane(__float_as_int(x[0])));
      if (lane == 0) l[0] = 0.f;                // threshold class: label forced 0

      // P  = prod over positives of (1 + exp(-|x|));  PM = sum pos min(x,0)
      // S  = sum over negatives of exp(x)  (no-max LSE: |x| < ~6)
      float Pr = 1.f, Sr = 0.f, PMr = 0.f, CNr = 0.f;
#pragma unroll
      for (int k = 0; k < 8; ++k) {
        bool  pos = (l[k] != 0.f);
        float sel = pos ? -fabsf(x[k]) : x[k];
        float e   = __builtin_amdgcn_exp2f(sel * L2E);
        Pr  *= fmaf(l[k], e, 1.f);
        Sr  += pos ? 0.f : e;
        PMr  = fmaf(l[k], fminf(x[k], 0.f), PMr);
        CNr += l[k];
      }
      P[r] = Pr; S[r] = Sr; PM[r] = PMr; CN[r] = CNr;
    }

    // wave64 reduce on VALU pipe: 8 independent chains (2 rows x 4 vars)
#define RED8(CTRL, RM)                                        \
    _Pragma("unroll")                                         \
    for (int r = 0; r < 2; ++r) {                             \
      S[r]  += dpp_get<CTRL, RM>(S[r],  0.f);                 \
      CN[r] += dpp_get<CTRL, RM>(CN[r], 0.f);                 \
      PM[r] += dpp_get<CTRL, RM>(PM[r], 0.f);                 \
      P[r]  *= dpp_get<CTRL, RM>(P[r],  1.f);                 \
    }
    RED8(0x111, 0xf)                            // row_shr:1
    RED8(0x112, 0xf)                            // row_shr:2
    RED8(0x114, 0xf)                            // row_shr:4
    RED8(0x118, 0xf)                            // row_shr:8
    RED8(0x142, 0xa)                            // row_bcast:15 (rows 1,3)
    RED8(0x143, 0xc)                            // row_bcast:31 (rows 2,3)
#undef RED8

#pragma unroll
    for (int r = 0; r < 2; ++r) {
      float Sw  = __int_as_float(__builtin_amdgcn_readlane(__float_as_int(S[r]),  63));
      float CNw = __int_as_float(__builtin_amdgcn_readlane(__float_as_int(CN[r]), 63));
      float PMw = __int_as_float(__builtin_amdgcn_readlane(__float_as_int(PM[r]), 63));
      float Pw  = __int_as_float(__builtin_amdgcn_readlane(__float_as_int(P[r]),  63));

      a_l2 += LN2 * __builtin_amdgcn_logf(Sw) - xz[r];   // lse - x0
      if (CNw > 0.f) {                          // wave-uniform branch
        float t0  = __builtin_amdgcn_exp2f(-fabsf(xz[r]) * L2E);
        float ls0 = fminf(-xz[r], 0.f) - LN2 * __builtin_amdgcn_logf(1.f + t0);
        a_term += ls0 + PMw - LN2 * __builtin_amdgcn_logf(Pw);
        a_cnt  += 1.f + CNw;
      }
    }
  }

  // block reduce: reuse staging LDS (all staging reads are done; barrier first)
  __syncthreads();
  if (lane == 0) { smem[wib] = a_term; smem[4 + wib] = a_cnt; smem[8 + wib] = a_l2; }
  __syncthreads();
  if (threadIdx.x == 0) {
    atomicAdd(&acc[0], (double)(smem[0] + smem[1] + smem[2]  + smem[3]));
    atomicAdd(&acc[1], (double)(smem[4] + smem[5] + smem[6]  + smem[7]));
    atomicAdd(&acc[2], (double)(smem[8] + smem[9] + smem[10] + smem[11]));
  }
}

__global__ void matloss_final(const double* __restrict__ acc, float* __restrict__ out) {
  out[0] = (float)(-acc[0] / acc[1] + acc[2] / (double)Bn);
}

extern "C" void kernel_launch(void* const* d_in, const int* in_sizes, int n_in,
                              void* d_out, int out_size, void* d_ws, size_t ws_size,
                              hipStream_t stream) {
  const float* logits = (const float*)d_in[0];
  const float* labels = (const float*)d_in[1];
  float* out = (float*)d_out;
  double* acc = (double*)d_ws;

  hipMemsetAsync(d_ws, 0, 3 * sizeof(double), stream);  // zero accumulators (capture-safe)
  matloss_main<<<512, 256, 0, stream>>>(logits, labels, acc);
  matloss_final<<<1, 1, 0, stream>>>(acc, out);
}